// Round 5
// baseline (833.058 us; speedup 1.0000x reference)
//
#include <hip/hip_runtime.h>
#include <hip/hip_bf16.h>
#include <math.h>

// Problem constants: B=1, S=32, N=512, C_M=256, C_Z=128, H=8, D=32
#define NH      8
#define HD      32
#define NN      512
#define SS      32
#define CM      256
#define CZ      128
#define NG      16     // global tokens
#define W_HALF  16     // W_LOCAL/2
#define MROWS   (SS * NN)   // 16384

typedef __attribute__((ext_vector_type(8))) __bf16 bf16x8;
typedef __attribute__((ext_vector_type(4))) float f32x4;

__device__ inline unsigned short f2bf(float x) {
    __hip_bfloat16 h = __float2bfloat16(x);
    return __builtin_bit_cast(unsigned short, h);
}
__device__ inline float bf2f(unsigned short u) {
    return __bfloat162float(__builtin_bit_cast(__hip_bfloat16, u));
}

// ---------------------------------------------------------------------------
// Convert msa fp32 [MROWS][CM] -> bf16 raw ushort, row-major. 8 elems/thread.
// ---------------------------------------------------------------------------
__global__ __launch_bounds__(256) void cvt_msa_kernel(
    const float* __restrict__ in, unsigned short* __restrict__ out)
{
    int i = (blockIdx.x * 256 + threadIdx.x) * 8;
    const float4* p = reinterpret_cast<const float4*>(in + i);
    float4 v0 = p[0], v1 = p[1];
    union { unsigned short u[8]; uint4 q; } o;
    o.u[0] = f2bf(v0.x); o.u[1] = f2bf(v0.y); o.u[2] = f2bf(v0.z); o.u[3] = f2bf(v0.w);
    o.u[4] = f2bf(v1.x); o.u[5] = f2bf(v1.y); o.u[6] = f2bf(v1.z); o.u[7] = f2bf(v1.w);
    *reinterpret_cast<uint4*>(out + i) = o.q;
}

// ---------------------------------------------------------------------------
// Convert + transpose weights: out[n][k] = bf16(in[k][n]), 256x256 each, 4 mats.
// ---------------------------------------------------------------------------
__global__ __launch_bounds__(256) void cvt_wT_kernel(
    const float* __restrict__ w0, const float* __restrict__ w1,
    const float* __restrict__ w2, const float* __restrict__ w3,
    unsigned short* __restrict__ o0, unsigned short* __restrict__ o1,
    unsigned short* __restrict__ o2, unsigned short* __restrict__ o3)
{
    int mat = blockIdx.y;
    const float* in = (mat == 0) ? w0 : (mat == 1) ? w1 : (mat == 2) ? w2 : w3;
    unsigned short* out = (mat == 0) ? o0 : (mat == 1) ? o1 : (mat == 2) ? o2 : o3;
    int o = blockIdx.x * 256 + threadIdx.x;     // 65536 elements
    int n = o >> 8, k = o & 255;
    out[o] = f2bf(in[k * 256 + n]);
}

// ---------------------------------------------------------------------------
// Pair bias   bias[h][n][m] = sum_c pair[n][m][c] * w_b[c][h] + b_b[h]
// One wave per (n,m); lane l holds c=2l,2l+1 (coalesced float2).
// ---------------------------------------------------------------------------
__global__ __launch_bounds__(256) void bias_kernel(
    const float* __restrict__ pair,
    const float* __restrict__ w_b,    // [CZ][NH]
    const float* __restrict__ b_b,    // [NH]
    float* __restrict__ bias)         // [NH][NN][NN]
{
    __shared__ __align__(16) float wbT[NH][130];
    int t = threadIdx.x;
    for (int idx = t; idx < CZ * NH; idx += 256) {
        int c = idx >> 3, h = idx & 7;
        wbT[h][c] = w_b[idx];
    }
    __syncthreads();

    int wave = t >> 6;
    int lane = t & 63;
    int pairIdx = blockIdx.x * 4 + wave;   // n*NN + m
    int n = pairIdx >> 9;
    int m = pairIdx & (NN - 1);

    const float2 pv = *reinterpret_cast<const float2*>(pair + (size_t)pairIdx * CZ + 2 * lane);

    float acc[NH];
#pragma unroll
    for (int h = 0; h < NH; ++h) {
        float2 w = *reinterpret_cast<const float2*>(&wbT[h][2 * lane]);
        acc[h] = pv.x * w.x + pv.y * w.y;
    }
#pragma unroll
    for (int h = 0; h < NH; ++h) {
#pragma unroll
        for (int off = 1; off < 64; off <<= 1)
            acc[h] += __shfl_xor(acc[h], off, 64);
    }
    if (lane < NH) {
        bias[(size_t)lane * (NN * NN) + (size_t)n * NN + m] = acc[lane] + b_b[lane];
    }
}

// ---------------------------------------------------------------------------
// bf16 MFMA GEMM: C[M,256] = A[M,256] @ W[256,256] + bias (+resid).
// A: bf16 row-major. WT: bf16 [n][k] (pre-transposed). Tile 128x64, BK=64.
// 4 waves (2m x 2n), wave tile 64x32 = 4x2 fragments of 16x16x32.
// LDS rows are 128B -> XOR chunk swizzle (chunk ^= row&7) applied on BOTH the
// global_load_lds source side and the ds_read side (involution, rule #21).
// BF16OUT: write bf16 (q/k/v path) else fp32 (y path).
// ---------------------------------------------------------------------------
template <bool RESID, bool BF16OUT>
__global__ __launch_bounds__(256) void mfma_gemm_kernel(
    const unsigned short* __restrict__ A,
    const unsigned short* __restrict__ WT,
    const float* __restrict__ bias,
    const float* __restrict__ resid,
    void* __restrict__ Cout)
{
    __shared__ __align__(16) unsigned short lds[12288];  // A: 128x64 (16KB), B: 64x64 (8KB)

    const int t = threadIdx.x;
    const int l = t & 63;
    const int w = t >> 6;
    const int wm = w >> 1, wn = w & 1;
    const int bn0 = blockIdx.x * 64;
    const int bm0 = blockIdx.y * 128;

    f32x4 acc[4][2] = {};

    for (int k0 = 0; k0 < 256; k0 += 64) {
        // stage A-tile: 16KB, 4 issues/wave of 1KB (64 lanes x 16B), linear LDS dest
#pragma unroll
        for (int j = 0; j < 4; ++j) {
            int Lbase = (j * 4 + w) * 1024;          // wave-uniform
            int L = Lbase + l * 16;
            int row = L >> 7;                        // 128B per row
            int cs = (L >> 4) & 7;
            int c = cs ^ (row & 7);                  // inverse swizzle on source
            const unsigned short* gp = A + (size_t)(bm0 + row) * 256 + k0 + c * 8;
            __builtin_amdgcn_global_load_lds(
                (const __attribute__((address_space(1))) void*)gp,
                (__attribute__((address_space(3))) void*)((char*)lds + Lbase), 16, 0, 0);
        }
        // stage B-tile: 8KB, 2 issues/wave
#pragma unroll
        for (int j = 0; j < 2; ++j) {
            int Lbase = 16384 + (j * 4 + w) * 1024;
            int L = (Lbase - 16384) + l * 16;
            int row = L >> 7;                        // 0..63 (= n index)
            int cs = (L >> 4) & 7;
            int c = cs ^ (row & 7);
            const unsigned short* gp = WT + (size_t)(bn0 + row) * 256 + k0 + c * 8;
            __builtin_amdgcn_global_load_lds(
                (const __attribute__((address_space(1))) void*)gp,
                (__attribute__((address_space(3))) void*)((char*)lds + Lbase), 16, 0, 0);
        }
        __syncthreads();   // compiler drains vmcnt before s_barrier

#pragma unroll
        for (int kh = 0; kh < 2; ++kh) {
            bf16x8 a[4], b[2];
#pragma unroll
            for (int m = 0; m < 4; ++m) {
                int row = wm * 64 + m * 16 + (l & 15);
                int c = (kh * 4 + (l >> 4)) ^ (row & 7);
                a[m] = *reinterpret_cast<const bf16x8*>((const char*)lds + row * 128 + c * 16);
            }
#pragma unroll
            for (int nf = 0; nf < 2; ++nf) {
                int nr = wn * 32 + nf * 16 + (l & 15);
                int c = (kh * 4 + (l >> 4)) ^ (nr & 7);
                b[nf] = *reinterpret_cast<const bf16x8*>((const char*)lds + 16384 + nr * 128 + c * 16);
            }
#pragma unroll
            for (int m = 0; m < 4; ++m)
#pragma unroll
                for (int nf = 0; nf < 2; ++nf)
                    acc[m][nf] = __builtin_amdgcn_mfma_f32_16x16x32_bf16(a[m], b[nf], acc[m][nf], 0, 0, 0);
        }
        __syncthreads();
    }

    // epilogue: C/D layout col=lane&15, row=(lane>>4)*4+reg  [m89 verified]
#pragma unroll
    for (int m = 0; m < 4; ++m) {
#pragma unroll
        for (int nf = 0; nf < 2; ++nf) {
            int col = bn0 + wn * 32 + nf * 16 + (l & 15);
            float bv = bias[col];
#pragma unroll
            for (int r = 0; r < 4; ++r) {
                int row = bm0 + wm * 64 + m * 16 + (l >> 4) * 4 + r;
                float val = acc[m][nf][r] + bv;
                if (RESID) val += resid[(size_t)row * 256 + col];
                if (BF16OUT)
                    ((unsigned short*)Cout)[(size_t)row * 256 + col] = f2bf(val);
                else
                    ((float*)Cout)[(size_t)row * 256 + col] = val;
            }
        }
    }
}

// ---------------------------------------------------------------------------
// Sparse attention. Block per (s,n). 256 threads = 8 heads x 32 d.
// q/k/v are bf16; softmax math fp32. Online softmax over allowed keys only
// (skipping masked keys == adding -1e9: exp underflows to exactly 0).
// Output bf16 (feeds out-projection MFMA A-operand).
// ---------------------------------------------------------------------------
__global__ __launch_bounds__(256) void attn_kernel(
    const unsigned short* __restrict__ q,   // [MROWS][CM] bf16
    const unsigned short* __restrict__ k,
    const unsigned short* __restrict__ v,
    const float* __restrict__ bias,         // [NH][NN][NN]
    unsigned short* __restrict__ out)       // [MROWS][CM] bf16
{
    const float scale = 0.17677669529663687f;  // 1/sqrt(32)
    int t = threadIdx.x;
    int sn = blockIdx.x;
    int n = sn & (NN - 1);
    int h = t >> 5;

    size_t rowbase = (size_t)sn * CM;
    float qv = bf2f(q[rowbase + t]) * scale;
    const float* biasrow = bias + (size_t)h * (NN * NN) + (size_t)n * NN;
    size_t kvbase = (size_t)(sn >> 9) * ((size_t)NN * CM);

    float m_run = -1e30f, l_run = 0.0f, acc = 0.0f;

#define ATT_BODY(mm)                                                        \
    {                                                                       \
        float kv = bf2f(k[kvbase + (size_t)(mm) * CM + t]);                 \
        float p = qv * kv;                                                  \
        p += __shfl_xor(p, 1);                                              \
        p += __shfl_xor(p, 2);                                              \
        p += __shfl_xor(p, 4);                                              \
        p += __shfl_xor(p, 8);                                              \
        p += __shfl_xor(p, 16);                                             \
        float x = p + biasrow[(mm)];                                        \
        float mn = fmaxf(m_run, x);                                         \
        float corr = __expf(m_run - mn);                                    \
        float e = __expf(x - mn);                                           \
        float vv = bf2f(v[kvbase + (size_t)(mm) * CM + t]);                 \
        l_run = l_run * corr + e;                                           \
        acc = acc * corr + e * vv;                                          \
        m_run = mn;                                                         \
    }

    int g_end = (n < NG) ? NN : NG;
    for (int m = 0; m < g_end; ++m) ATT_BODY(m);
    if (n >= NG) {
        int lo = n - W_HALF; if (lo < NG) lo = NG;
        int hi = n + W_HALF; if (hi > NN - 1) hi = NN - 1;
        for (int m = lo; m <= hi; ++m) ATT_BODY(m);
    }
#undef ATT_BODY

    out[rowbase + t] = f2bf(acc / l_run);
}

// ---------------------------------------------------------------------------
// LayerNorm over CM=256, in place. One wave per row.
// ---------------------------------------------------------------------------
__global__ __launch_bounds__(256) void ln_kernel(
    const float* __restrict__ y,
    const float* __restrict__ g,
    const float* __restrict__ b,
    float* __restrict__ outp)
{
    int t = threadIdx.x;
    int wave = t >> 6, lane = t & 63;
    int row = blockIdx.x * 4 + wave;

    const float4 yv = *reinterpret_cast<const float4*>(y + (size_t)row * CM + lane * 4);
    float s  = yv.x + yv.y + yv.z + yv.w;
    float sq = yv.x * yv.x + yv.y * yv.y + yv.z * yv.z + yv.w * yv.w;
#pragma unroll
    for (int off = 1; off < 64; off <<= 1) {
        s  += __shfl_xor(s, off, 64);
        sq += __shfl_xor(sq, off, 64);
    }
    float mu  = s * (1.0f / CM);
    float var = sq * (1.0f / CM) - mu * mu;
    float r   = rsqrtf(var + 1e-5f);

    float4 gv = *reinterpret_cast<const float4*>(g + lane * 4);
    float4 bv = *reinterpret_cast<const float4*>(b + lane * 4);
    float4 o;
    o.x = (yv.x - mu) * r * gv.x + bv.x;
    o.y = (yv.y - mu) * r * gv.y + bv.y;
    o.z = (yv.z - mu) * r * gv.z + bv.z;
    o.w = (yv.w - mu) * r * gv.w + bv.w;
    *reinterpret_cast<float4*>(outp + (size_t)row * CM + lane * 4) = o;
}

// ---------------------------------------------------------------------------
extern "C" void kernel_launch(void* const* d_in, const int* in_sizes, int n_in,
                              void* d_out, int out_size, void* d_ws, size_t ws_size,
                              hipStream_t stream)
{
    const float* msa  = (const float*)d_in[0];
    const float* pair = (const float*)d_in[1];
    const float* w_q  = (const float*)d_in[2];
    const float* b_q  = (const float*)d_in[3];
    const float* w_k  = (const float*)d_in[4];
    const float* b_k  = (const float*)d_in[5];
    const float* w_v  = (const float*)d_in[6];
    const float* b_v  = (const float*)d_in[7];
    const float* w_o  = (const float*)d_in[8];
    const float* b_o  = (const float*)d_in[9];
    const float* w_b  = (const float*)d_in[10];
    const float* b_b  = (const float*)d_in[11];
    const float* ln_g = (const float*)d_in[12];
    const float* ln_b = (const float*)d_in[13];
    float* out = (float*)d_out;

    // workspace layout (48.5 MB total)
    float* ws   = (float*)d_ws;
    float* bias = ws;                                    // 8 MB
    unsigned short* q_bf   = (unsigned short*)(bias + (size_t)NH * NN * NN);  // 8 MB each
    unsigned short* k_bf   = q_bf + (size_t)MROWS * CM;
    unsigned short* v_bf   = k_bf + (size_t)MROWS * CM;
    unsigned short* msa_bf = v_bf + (size_t)MROWS * CM;  // 8 MB
    unsigned short* ao_bf  = msa_bf + (size_t)MROWS * CM; // 8 MB
    unsigned short* wqT = ao_bf + (size_t)MROWS * CM;    // 128 KB each
    unsigned short* wkT = wqT + CM * CM;
    unsigned short* wvT = wkT + CM * CM;
    unsigned short* woT = wvT + CM * CM;

    // 1. conversions
    cvt_msa_kernel<<<(MROWS * CM) / (256 * 8), 256, 0, stream>>>(msa, msa_bf);
    cvt_wT_kernel<<<dim3(CM * CM / 256, 4), 256, 0, stream>>>(
        w_q, w_k, w_v, w_o, wqT, wkT, wvT, woT);

    // 2. pair bias
    bias_kernel<<<(NN * NN) / 4, 256, 0, stream>>>(pair, w_b, b_b, bias);

    // 3. Q/K/V projections (bf16 MFMA, bf16 outputs)
    dim3 gg(CM / 64, MROWS / 128);
    mfma_gemm_kernel<false, true><<<gg, 256, 0, stream>>>(msa_bf, wqT, b_q, nullptr, q_bf);
    mfma_gemm_kernel<false, true><<<gg, 256, 0, stream>>>(msa_bf, wkT, b_k, nullptr, k_bf);
    mfma_gemm_kernel<false, true><<<gg, 256, 0, stream>>>(msa_bf, wvT, b_v, nullptr, v_bf);

    // 4. sparse attention -> bf16 output
    attn_kernel<<<MROWS, 256, 0, stream>>>(q_bf, k_bf, v_bf, bias, ao_bf);

    // 5. output projection + residual -> d_out (fp32 y)
    mfma_gemm_kernel<true, false><<<gg, 256, 0, stream>>>(ao_bf, woT, b_o, msa, out);

    // 6. LayerNorm in place
    ln_kernel<<<MROWS / 4, 256, 0, stream>>>(out, ln_g, ln_b, out);
}

// Round 6
// 311.362 us; speedup vs baseline: 2.6755x; 2.6755x over previous
//
#include <hip/hip_runtime.h>
#include <hip/hip_bf16.h>
#include <math.h>

// Problem constants: B=1, S=32, N=512, C_M=256, C_Z=128, H=8, D=32
#define NH      8
#define HD      32
#define NN      512
#define SS      32
#define CM      256
#define CZ      128
#define NG      16     // global tokens
#define W_HALF  16     // W_LOCAL/2
#define MROWS   (SS * NN)   // 16384

typedef __attribute__((ext_vector_type(8))) __bf16 bf16x8;
typedef __attribute__((ext_vector_type(4))) float f32x4;

__device__ inline unsigned short f2bf(float x) {
    __hip_bfloat16 h = __float2bfloat16(x);
    return __builtin_bit_cast(unsigned short, h);
}
__device__ inline float bflo(unsigned u) { return __uint_as_float(u << 16); }
__device__ inline float bfhi(unsigned u) { return __uint_as_float(u & 0xffff0000u); }
__device__ inline float bf1(unsigned short u) { return __uint_as_float((unsigned)u << 16); }

// ---------------------------------------------------------------------------
// Convert msa fp32 [MROWS][CM] -> bf16 raw ushort, row-major. 8 elems/thread.
// ---------------------------------------------------------------------------
__global__ __launch_bounds__(256) void cvt_msa_kernel(
    const float* __restrict__ in, unsigned short* __restrict__ out)
{
    int i = (blockIdx.x * 256 + threadIdx.x) * 8;
    const float4* p = reinterpret_cast<const float4*>(in + i);
    float4 v0 = p[0], v1 = p[1];
    union { unsigned short u[8]; uint4 q; } o;
    o.u[0] = f2bf(v0.x); o.u[1] = f2bf(v0.y); o.u[2] = f2bf(v0.z); o.u[3] = f2bf(v0.w);
    o.u[4] = f2bf(v1.x); o.u[5] = f2bf(v1.y); o.u[6] = f2bf(v1.z); o.u[7] = f2bf(v1.w);
    *reinterpret_cast<uint4*>(out + i) = o.q;
}

// ---------------------------------------------------------------------------
// Convert + transpose weights: out[n][k] = bf16(in[k][n]), 256x256 each, 4 mats.
// ---------------------------------------------------------------------------
__global__ __launch_bounds__(256) void cvt_wT_kernel(
    const float* __restrict__ w0, const float* __restrict__ w1,
    const float* __restrict__ w2, const float* __restrict__ w3,
    unsigned short* __restrict__ o0, unsigned short* __restrict__ o1,
    unsigned short* __restrict__ o2, unsigned short* __restrict__ o3)
{
    int mat = blockIdx.y;
    const float* in = (mat == 0) ? w0 : (mat == 1) ? w1 : (mat == 2) ? w2 : w3;
    unsigned short* out = (mat == 0) ? o0 : (mat == 1) ? o1 : (mat == 2) ? o2 : o3;
    int o = blockIdx.x * 256 + threadIdx.x;     // 65536 elements
    int n = o >> 8, k = o & 255;
    out[o] = f2bf(in[k * 256 + n]);
}

// ---------------------------------------------------------------------------
// Sparse pair bias. Computes ONLY the (n,m) pairs attention reads, into three
// attention-friendly layouts (all fp32, coalesced on the inner index):
//   biasD[h][o][n] = bias(n, n-16+o)      o in [0,33)   (window diagonals)
//   biasG[h][m][n] = bias(n, m)           m in [0,16)   (global columns)
//   biasR[h][q][m] = bias(q, m)           q in [0,16)   (dense rows)
// One wave per (n,m) pair; lane l holds pair channels 2l,2l+1.
// ---------------------------------------------------------------------------
#define JOBS_D  (512 * 33)
#define JOBS_G  (512 * 16)
#define JOBS_R  (512 * 16)
#define NJOBS   (JOBS_D + JOBS_G + JOBS_R)

__global__ __launch_bounds__(256) void bias_kernel(
    const float* __restrict__ pair,
    const float* __restrict__ w_b,    // [CZ][NH]
    const float* __restrict__ b_b,    // [NH]
    float* __restrict__ biasD,
    float* __restrict__ biasG,
    float* __restrict__ biasR)
{
    const int t = threadIdx.x;
    const int wave = t >> 6, lane = t & 63;
    int job = blockIdx.x * 4 + wave;
    if (job >= NJOBS) return;

    int n, m;
    float* oaddr;
    int hstride;
    if (job < JOBS_D) {
        n = job / 33;
        int o = job - n * 33;
        m = n + o - 16;
        if (m < 0 || m >= 512) return;       // wave-uniform
        oaddr = biasD + o * 512 + n;
        hstride = 33 * 512;
    } else if (job < JOBS_D + JOBS_G) {
        int i = job - JOBS_D;
        n = i >> 4; m = i & 15;
        oaddr = biasG + m * 512 + n;
        hstride = 16 * 512;
    } else {
        int i = job - (JOBS_D + JOBS_G);
        n = i & 15; m = i >> 4;              // n is the dense query row
        oaddr = biasR + n * 512 + m;
        hstride = 16 * 512;
    }

    const float2 pv = *reinterpret_cast<const float2*>(
        pair + ((size_t)n * 512 + m) * CZ + 2 * lane);
    // w_b rows 2*lane, 2*lane+1 (8 floats each)
    const float4 a0 = ((const float4*)(w_b + (2 * lane) * NH))[0];
    const float4 a1 = ((const float4*)(w_b + (2 * lane) * NH))[1];
    const float4 b0 = ((const float4*)(w_b + (2 * lane + 1) * NH))[0];
    const float4 b1 = ((const float4*)(w_b + (2 * lane + 1) * NH))[1];

    float acc8[8];
    acc8[0] = pv.x * a0.x + pv.y * b0.x;
    acc8[1] = pv.x * a0.y + pv.y * b0.y;
    acc8[2] = pv.x * a0.z + pv.y * b0.z;
    acc8[3] = pv.x * a0.w + pv.y * b0.w;
    acc8[4] = pv.x * a1.x + pv.y * b1.x;
    acc8[5] = pv.x * a1.y + pv.y * b1.y;
    acc8[6] = pv.x * a1.z + pv.y * b1.z;
    acc8[7] = pv.x * a1.w + pv.y * b1.w;
#pragma unroll
    for (int h = 0; h < 8; ++h) {
#pragma unroll
        for (int off = 1; off < 64; off <<= 1)
            acc8[h] += __shfl_xor(acc8[h], off, 64);
    }
    if (lane < 8) {
        float v = acc8[0];
#pragma unroll
        for (int h = 1; h < 8; ++h) v = (lane == h) ? acc8[h] : v;
        oaddr[(size_t)lane * hstride] = v + b_b[lane];
    }
}

// ---------------------------------------------------------------------------
// bf16 MFMA GEMM: C[M,256] = A[M,256] @ W[256,256] + bias (+resid).
// (verified round-5: absmax 0.031) Tile 128x64, BK=64, 4 waves, XOR swizzle.
// ---------------------------------------------------------------------------
template <bool RESID, bool BF16OUT>
__global__ __launch_bounds__(256) void mfma_gemm_kernel(
    const unsigned short* __restrict__ A,
    const unsigned short* __restrict__ WT,
    const float* __restrict__ bias,
    const float* __restrict__ resid,
    void* __restrict__ Cout)
{
    __shared__ __align__(16) unsigned short lds[12288];  // A: 128x64 (16KB), B: 64x64 (8KB)

    const int t = threadIdx.x;
    const int l = t & 63;
    const int w = t >> 6;
    const int wm = w >> 1, wn = w & 1;
    const int bn0 = blockIdx.x * 64;
    const int bm0 = blockIdx.y * 128;

    f32x4 acc[4][2] = {};

    for (int k0 = 0; k0 < 256; k0 += 64) {
#pragma unroll
        for (int j = 0; j < 4; ++j) {
            int Lbase = (j * 4 + w) * 1024;
            int L = Lbase + l * 16;
            int row = L >> 7;
            int cs = (L >> 4) & 7;
            int c = cs ^ (row & 7);
            const unsigned short* gp = A + (size_t)(bm0 + row) * 256 + k0 + c * 8;
            __builtin_amdgcn_global_load_lds(
                (const __attribute__((address_space(1))) void*)gp,
                (__attribute__((address_space(3))) void*)((char*)lds + Lbase), 16, 0, 0);
        }
#pragma unroll
        for (int j = 0; j < 2; ++j) {
            int Lbase = 16384 + (j * 4 + w) * 1024;
            int L = (Lbase - 16384) + l * 16;
            int row = L >> 7;
            int cs = (L >> 4) & 7;
            int c = cs ^ (row & 7);
            const unsigned short* gp = WT + (size_t)(bn0 + row) * 256 + k0 + c * 8;
            __builtin_amdgcn_global_load_lds(
                (const __attribute__((address_space(1))) void*)gp,
                (__attribute__((address_space(3))) void*)((char*)lds + Lbase), 16, 0, 0);
        }
        __syncthreads();

#pragma unroll
        for (int kh = 0; kh < 2; ++kh) {
            bf16x8 a[4], b[2];
#pragma unroll
            for (int m = 0; m < 4; ++m) {
                int row = wm * 64 + m * 16 + (l & 15);
                int c = (kh * 4 + (l >> 4)) ^ (row & 7);
                a[m] = *reinterpret_cast<const bf16x8*>((const char*)lds + row * 128 + c * 16);
            }
#pragma unroll
            for (int nf = 0; nf < 2; ++nf) {
                int nr = wn * 32 + nf * 16 + (l & 15);
                int c = (kh * 4 + (l >> 4)) ^ (nr & 7);
                b[nf] = *reinterpret_cast<const bf16x8*>((const char*)lds + 16384 + nr * 128 + c * 16);
            }
#pragma unroll
            for (int m = 0; m < 4; ++m)
#pragma unroll
                for (int nf = 0; nf < 2; ++nf)
                    acc[m][nf] = __builtin_amdgcn_mfma_f32_16x16x32_bf16(a[m], b[nf], acc[m][nf], 0, 0, 0);
        }
        __syncthreads();
    }

#pragma unroll
    for (int m = 0; m < 4; ++m) {
#pragma unroll
        for (int nf = 0; nf < 2; ++nf) {
            int col = bn0 + wn * 32 + nf * 16 + (l & 15);
            float bv = bias[col];
#pragma unroll
            for (int r = 0; r < 4; ++r) {
                int row = bm0 + wm * 64 + m * 16 + (l >> 4) * 4 + r;
                float val = acc[m][nf][r] + bv;
                if (RESID) val += resid[(size_t)row * 256 + col];
                if (BF16OUT)
                    ((unsigned short*)Cout)[(size_t)row * 256 + col] = f2bf(val);
                else
                    ((float*)Cout)[(size_t)row * 256 + col] = val;
            }
        }
    }
}

// ---------------------------------------------------------------------------
// Sparse attention v2. Block = (s, h), 512 threads, grid.y selects path:
//  y==0 (window rows q>=16): lane-per-query. K,V staged d-major in LDS
//    (kT[d][m]); per key-pair one b32 LDS read serves two keys; dot over d is
//    32 lane-local FMAs -> NO cross-lane ops per key. Conditional-rescale
//    online softmax. Global keys [0,16) then window [q-16,q+16] (m>=16).
//  y==1 (dense rows q<16): 8 waves x 2 queries; 64 lanes x 8 keys each with
//    local online softmax, then one 64-lane butterfly merge per query.
// ---------------------------------------------------------------------------
__global__ __launch_bounds__(512) void attn2_kernel(
    const unsigned short* __restrict__ qb,  // [sn][hd] bf16
    const unsigned short* __restrict__ kb,
    const unsigned short* __restrict__ vb,
    const float* __restrict__ biasD,
    const float* __restrict__ biasG,
    const float* __restrict__ biasR,
    unsigned short* __restrict__ outp)      // [sn][hd] bf16
{
    __shared__ unsigned short kT[32][512];  // 32 KB
    __shared__ unsigned short vT[32][512];  // 32 KB

    const int t = threadIdx.x;
    const int h = blockIdx.x >> 5;
    const int s = blockIdx.x & 31;
    const float scale = 0.17677669529663687f;  // 1/sqrt(32)

    // ---- stage K,V transposed: thread t owns source row n=t ----
    {
        const unsigned short* kr = kb + ((size_t)((s << 9) + t)) * 256 + h * 32;
        const unsigned short* vr = vb + ((size_t)((s << 9) + t)) * 256 + h * 32;
        union { uint4 q4[4]; unsigned short u[32]; } kk, vv;
#pragma unroll
        for (int i = 0; i < 4; ++i) {
            kk.q4[i] = ((const uint4*)kr)[i];
            vv.q4[i] = ((const uint4*)vr)[i];
        }
#pragma unroll
        for (int d = 0; d < 32; ++d) {
            kT[d][t] = kk.u[d];
            vT[d][t] = vv.u[d];
        }
    }
    __syncthreads();

    if (blockIdx.y == 0) {
        // ================= window path: q = t, rows 16..511 =================
        const int q = t;
        if (q < 16) return;

        float qr[32];
        {
            const unsigned short* qrow = qb + ((size_t)((s << 9) + q)) * 256 + h * 32;
            union { uint4 q4[4]; unsigned short u[32]; } qq;
#pragma unroll
            for (int i = 0; i < 4; ++i) qq.q4[i] = ((const uint4*)qrow)[i];
#pragma unroll
            for (int d = 0; d < 32; ++d) qr[d] = bf1(qq.u[d]) * scale;
        }

        float m_run = -1e30f, l_run = 0.f;
        float acc[32];
#pragma unroll
        for (int d = 0; d < 32; ++d) acc[d] = 0.f;

        // ---- global keys m in [0,16), 8 aligned pairs ----
        const float* bG = biasG + (size_t)(h * 16) * 512 + q;
        for (int i = 0; i < 8; ++i) {
            const int m0 = 2 * i;
            float s0 = 0.f, s1 = 0.f;
#pragma unroll
            for (int d = 0; d < 32; ++d) {
                unsigned u = *(const unsigned*)&kT[d][m0];
                s0 = fmaf(qr[d], bflo(u), s0);
                s1 = fmaf(qr[d], bfhi(u), s1);
            }
            float x0 = s0 + bG[(size_t)m0 * 512];
            float x1 = s1 + bG[(size_t)(m0 + 1) * 512];
            float mx = fmaxf(x0, x1);
            if (mx > m_run) {
                float corr = __expf(m_run - mx);
                m_run = mx; l_run *= corr;
#pragma unroll
                for (int d = 0; d < 32; ++d) acc[d] *= corr;
            }
            float e0 = __expf(x0 - m_run);
            float e1 = __expf(x1 - m_run);
            l_run += e0 + e1;
#pragma unroll
            for (int d = 0; d < 32; ++d) {
                unsigned u = *(const unsigned*)&vT[d][m0];
                acc[d] = fmaf(e0, bflo(u), acc[d]);
                acc[d] = fmaf(e1, bfhi(u), acc[d]);
            }
        }

        // ---- window keys [q-16, q+16] clipped to [16,511], 18 aligned pairs ----
        const int lo = (q - 16 < 16) ? 16 : q - 16;
        const int hi = (q + 16 > 511) ? 511 : q + 16;
        const int start = (q - 16) & ~1;
        const float* bD = biasD + (size_t)(h * 33) * 512 + q;
        for (int i = 0; i < 18; ++i) {
            const int m0 = start + 2 * i;
            const int mc = (m0 > 510) ? 510 : m0;     // LDS-safe, masked anyway
            const bool v0 = (m0 >= lo) & (m0 <= hi);
            const bool v1 = (m0 + 1 >= lo) & (m0 + 1 <= hi);
            float s0 = 0.f, s1 = 0.f;
#pragma unroll
            for (int d = 0; d < 32; ++d) {
                unsigned u = *(const unsigned*)&kT[d][mc];
                s0 = fmaf(qr[d], bflo(u), s0);
                s1 = fmaf(qr[d], bfhi(u), s1);
            }
            int o0 = m0 - q + 16;     o0 = o0 < 0 ? 0 : (o0 > 32 ? 32 : o0);
            int o1 = m0 + 1 - q + 16; o1 = o1 < 0 ? 0 : (o1 > 32 ? 32 : o1);
            float x0 = v0 ? (s0 + bD[(size_t)o0 * 512]) : -1e30f;
            float x1 = v1 ? (s1 + bD[(size_t)o1 * 512]) : -1e30f;
            float mx = fmaxf(x0, x1);
            if (mx > m_run) {
                float corr = __expf(m_run - mx);
                m_run = mx; l_run *= corr;
#pragma unroll
                for (int d = 0; d < 32; ++d) acc[d] *= corr;
            }
            float e0 = v0 ? __expf(x0 - m_run) : 0.f;
            float e1 = v1 ? __expf(x1 - m_run) : 0.f;
            l_run += e0 + e1;
#pragma unroll
            for (int d = 0; d < 32; ++d) {
                unsigned u = *(const unsigned*)&vT[d][mc];
                acc[d] = fmaf(e0, bflo(u), acc[d]);
                acc[d] = fmaf(e1, bfhi(u), acc[d]);
            }
        }

        // ---- write ----
        const float inv = 1.0f / l_run;
        union { uint4 q4[4]; unsigned short u[32]; } oo;
#pragma unroll
        for (int d = 0; d < 32; ++d) oo.u[d] = f2bf(acc[d] * inv);
        unsigned short* orow = outp + ((size_t)((s << 9) + q)) * 256 + h * 32;
#pragma unroll
        for (int i = 0; i < 4; ++i) ((uint4*)orow)[i] = oo.q4[i];
    } else {
        // ================= dense path: rows 0..15, all 512 keys =============
        const int wv = t >> 6, lane = t & 63;
        for (int qi = 0; qi < 2; ++qi) {
            const int q = wv * 2 + qi;
            float qr[32];
            {
                const unsigned short* qrow = qb + ((size_t)((s << 9) + q)) * 256 + h * 32;
                union { uint4 q4[4]; unsigned short u[32]; } qq;
#pragma unroll
                for (int i = 0; i < 4; ++i) qq.q4[i] = ((const uint4*)qrow)[i];
#pragma unroll
                for (int d = 0; d < 32; ++d) qr[d] = bf1(qq.u[d]) * scale;
            }
            float m_loc = -1e30f, l_loc = 0.f;
            float accl[32];
#pragma unroll
            for (int d = 0; d < 32; ++d) accl[d] = 0.f;

            const float* bR = biasR + (size_t)(h * 16 + q) * 512;
            for (int j = 0; j < 8; ++j) {
                const int m = j * 64 + lane;
                float sc = 0.f;
#pragma unroll
                for (int d = 0; d < 32; ++d)
                    sc = fmaf(qr[d], bf1(kT[d][m]), sc);
                float x = sc + bR[m];
                if (x > m_loc) {
                    float corr = __expf(m_loc - x);
                    m_loc = x; l_loc *= corr;
#pragma unroll
                    for (int d = 0; d < 32; ++d) accl[d] *= corr;
                }
                float e = __expf(x - m_loc);
                l_loc += e;
#pragma unroll
                for (int d = 0; d < 32; ++d)
                    accl[d] = fmaf(e, bf1(vT[d][m]), accl[d]);
            }
            // merge 64 lanes
            float mg = m_loc;
#pragma unroll
            for (int off = 1; off < 64; off <<= 1)
                mg = fmaxf(mg, __shfl_xor(mg, off, 64));
            float cf = __expf(m_loc - mg);
            float lg = l_loc * cf;
#pragma unroll
            for (int off = 1; off < 64; off <<= 1)
                lg += __shfl_xor(lg, off, 64);
            const float inv = 1.0f / lg;
            union { uint4 q4[4]; unsigned short u[32]; } oo;
#pragma unroll
            for (int d = 0; d < 32; ++d) {
                float a = accl[d] * cf;
#pragma unroll
                for (int off = 1; off < 64; off <<= 1)
                    a += __shfl_xor(a, off, 64);
                oo.u[d] = f2bf(a * inv);
            }
            if (lane == 0) {
                unsigned short* orow = outp + ((size_t)((s << 9) + q)) * 256 + h * 32;
#pragma unroll
                for (int i = 0; i < 4; ++i) ((uint4*)orow)[i] = oo.q4[i];
            }
        }
    }
}

// ---------------------------------------------------------------------------
// LayerNorm over CM=256, in place. One wave per row.
// ---------------------------------------------------------------------------
__global__ __launch_bounds__(256) void ln_kernel(
    const float* __restrict__ y,
    const float* __restrict__ g,
    const float* __restrict__ b,
    float* __restrict__ outp)
{
    int t = threadIdx.x;
    int wave = t >> 6, lane = t & 63;
    int row = blockIdx.x * 4 + wave;

    const float4 yv = *reinterpret_cast<const float4*>(y + (size_t)row * CM + lane * 4);
    float s  = yv.x + yv.y + yv.z + yv.w;
    float sq = yv.x * yv.x + yv.y * yv.y + yv.z * yv.z + yv.w * yv.w;
#pragma unroll
    for (int off = 1; off < 64; off <<= 1) {
        s  += __shfl_xor(s, off, 64);
        sq += __shfl_xor(sq, off, 64);
    }
    float mu  = s * (1.0f / CM);
    float var = sq * (1.0f / CM) - mu * mu;
    float r   = rsqrtf(var + 1e-5f);

    float4 gv = *reinterpret_cast<const float4*>(g + lane * 4);
    float4 bv = *reinterpret_cast<const float4*>(b + lane * 4);
    float4 o;
    o.x = (yv.x - mu) * r * gv.x + bv.x;
    o.y = (yv.y - mu) * r * gv.y + bv.y;
    o.z = (yv.z - mu) * r * gv.z + bv.z;
    o.w = (yv.w - mu) * r * gv.w + bv.w;
    *reinterpret_cast<float4*>(outp + (size_t)row * CM + lane * 4) = o;
}

// ---------------------------------------------------------------------------
extern "C" void kernel_launch(void* const* d_in, const int* in_sizes, int n_in,
                              void* d_out, int out_size, void* d_ws, size_t ws_size,
                              hipStream_t stream)
{
    const float* msa  = (const float*)d_in[0];
    const float* pair = (const float*)d_in[1];
    const float* w_q  = (const float*)d_in[2];
    const float* b_q  = (const float*)d_in[3];
    const float* w_k  = (const float*)d_in[4];
    const float* b_k  = (const float*)d_in[5];
    const float* w_v  = (const float*)d_in[6];
    const float* b_v  = (const float*)d_in[7];
    const float* w_o  = (const float*)d_in[8];
    const float* b_o  = (const float*)d_in[9];
    const float* w_b  = (const float*)d_in[10];
    const float* b_b  = (const float*)d_in[11];
    const float* ln_g = (const float*)d_in[12];
    const float* ln_b = (const float*)d_in[13];
    float* out = (float*)d_out;

    // workspace layout (~43.5 MB)
    float* ws    = (float*)d_ws;
    float* biasD = ws;                           // 8*33*512 = 135168 f
    float* biasG = biasD + 8 * 33 * 512;         // 8*16*512 =  65536 f
    float* biasR = biasG + 8 * 16 * 512;         // 8*16*512 =  65536 f
    unsigned short* q_bf   = (unsigned short*)(biasR + 8 * 16 * 512);
    unsigned short* k_bf   = q_bf + (size_t)MROWS * CM;
    unsigned short* v_bf   = k_bf + (size_t)MROWS * CM;
    unsigned short* msa_bf = v_bf + (size_t)MROWS * CM;
    unsigned short* ao_bf  = msa_bf + (size_t)MROWS * CM;
    unsigned short* wqT = ao_bf + (size_t)MROWS * CM;
    unsigned short* wkT = wqT + CM * CM;
    unsigned short* wvT = wkT + CM * CM;
    unsigned short* woT = wvT + CM * CM;

    // 1. conversions
    cvt_msa_kernel<<<(MROWS * CM) / (256 * 8), 256, 0, stream>>>(msa, msa_bf);
    cvt_wT_kernel<<<dim3(CM * CM / 256, 4), 256, 0, stream>>>(
        w_q, w_k, w_v, w_o, wqT, wkT, wvT, woT);

    // 2. sparse pair bias (only allowed pairs)
    bias_kernel<<<(NJOBS + 3) / 4, 256, 0, stream>>>(
        pair, w_b, b_b, biasD, biasG, biasR);

    // 3. Q/K/V projections (bf16 MFMA, bf16 outputs)
    dim3 gg(CM / 64, MROWS / 128);
    mfma_gemm_kernel<false, true><<<gg, 256, 0, stream>>>(msa_bf, wqT, b_q, nullptr, q_bf);
    mfma_gemm_kernel<false, true><<<gg, 256, 0, stream>>>(msa_bf, wkT, b_k, nullptr, k_bf);
    mfma_gemm_kernel<false, true><<<gg, 256, 0, stream>>>(msa_bf, wvT, b_v, nullptr, v_bf);

    // 4. sparse attention v2 -> bf16 output
    attn2_kernel<<<dim3(256, 2), 512, 0, stream>>>(
        q_bf, k_bf, v_bf, biasD, biasG, biasR, ao_bf);

    // 5. output projection + residual -> d_out (fp32 y)
    mfma_gemm_kernel<true, false><<<gg, 256, 0, stream>>>(ao_bf, woT, b_o, msa, out);

    // 6. LayerNorm in place
    ln_kernel<<<MROWS / 4, 256, 0, stream>>>(out, ln_g, ln_b, out);
}

// Round 10
// 306.672 us; speedup vs baseline: 2.7165x; 1.0153x over previous
//
#include <hip/hip_runtime.h>
#include <hip/hip_bf16.h>
#include <math.h>

// Problem constants: B=1, S=32, N=512, C_M=256, C_Z=128, H=8, D=32
#define NH      8
#define HD      32
#define NN      512
#define SS      32
#define CM      256
#define CZ      128
#define NG      16     // global tokens
#define W_HALF  16     // W_LOCAL/2
#define MROWS   (SS * NN)   // 16384

typedef __attribute__((ext_vector_type(8))) __bf16 bf16x8;
typedef __attribute__((ext_vector_type(4))) float f32x4;

__device__ inline unsigned short f2bf(float x) {
    __hip_bfloat16 h = __float2bfloat16(x);
    return __builtin_bit_cast(unsigned short, h);
}
__device__ inline float bflo(unsigned u) { return __uint_as_float(u << 16); }
__device__ inline float bfhi(unsigned u) { return __uint_as_float(u & 0xffff0000u); }
__device__ inline float bf1(unsigned short u) { return __uint_as_float((unsigned)u << 16); }

// ---------------------------------------------------------------------------
// Convert msa fp32 [MROWS][CM] -> bf16 raw ushort, row-major. 8 elems/thread.
// ---------------------------------------------------------------------------
__global__ __launch_bounds__(256) void cvt_msa_kernel(
    const float* __restrict__ in, unsigned short* __restrict__ out)
{
    int i = (blockIdx.x * 256 + threadIdx.x) * 8;
    const float4* p = reinterpret_cast<const float4*>(in + i);
    float4 v0 = p[0], v1 = p[1];
    union { unsigned short u[8]; uint4 q; } o;
    o.u[0] = f2bf(v0.x); o.u[1] = f2bf(v0.y); o.u[2] = f2bf(v0.z); o.u[3] = f2bf(v0.w);
    o.u[4] = f2bf(v1.x); o.u[5] = f2bf(v1.y); o.u[6] = f2bf(v1.z); o.u[7] = f2bf(v1.w);
    *reinterpret_cast<uint4*>(out + i) = o.q;
}

// ---------------------------------------------------------------------------
// Convert + transpose weights: out[n][k] = bf16(in[k][n]), 256x256 each, 4 mats.
// ---------------------------------------------------------------------------
__global__ __launch_bounds__(256) void cvt_wT_kernel(
    const float* __restrict__ w0, const float* __restrict__ w1,
    const float* __restrict__ w2, const float* __restrict__ w3,
    unsigned short* __restrict__ o0, unsigned short* __restrict__ o1,
    unsigned short* __restrict__ o2, unsigned short* __restrict__ o3)
{
    int mat = blockIdx.y;
    const float* in = (mat == 0) ? w0 : (mat == 1) ? w1 : (mat == 2) ? w2 : w3;
    unsigned short* out = (mat == 0) ? o0 : (mat == 1) ? o1 : (mat == 2) ? o2 : o3;
    int o = blockIdx.x * 256 + threadIdx.x;     // 65536 elements
    int n = o >> 8, k = o & 255;
    out[o] = f2bf(in[k * 256 + n]);
}

// ---------------------------------------------------------------------------
// Sparse pair bias (round-6 verified). Only the (n,m) pairs attention reads:
//   biasD[h][o][n] = bias(n, n-16+o)   o in [0,33)
//   biasG[h][m][n] = bias(n, m)        m in [0,16)
//   biasR[h][q][m] = bias(q, m)        q in [0,16)
// ---------------------------------------------------------------------------
#define JOBS_D  (512 * 33)
#define JOBS_G  (512 * 16)
#define JOBS_R  (512 * 16)
#define NJOBS   (JOBS_D + JOBS_G + JOBS_R)

__global__ __launch_bounds__(256) void bias_kernel(
    const float* __restrict__ pair,
    const float* __restrict__ w_b,    // [CZ][NH]
    const float* __restrict__ b_b,    // [NH]
    float* __restrict__ biasD,
    float* __restrict__ biasG,
    float* __restrict__ biasR)
{
    const int t = threadIdx.x;
    const int wave = t >> 6, lane = t & 63;
    int job = blockIdx.x * 4 + wave;
    if (job >= NJOBS) return;

    int n, m;
    float* oaddr;
    int hstride;
    if (job < JOBS_D) {
        n = job / 33;
        int o = job - n * 33;
        m = n + o - 16;
        if (m < 0 || m >= 512) return;       // wave-uniform
        oaddr = biasD + o * 512 + n;
        hstride = 33 * 512;
    } else if (job < JOBS_D + JOBS_G) {
        int i = job - JOBS_D;
        n = i >> 4; m = i & 15;
        oaddr = biasG + m * 512 + n;
        hstride = 16 * 512;
    } else {
        int i = job - (JOBS_D + JOBS_G);
        n = i & 15; m = i >> 4;              // n is the dense query row
        oaddr = biasR + n * 512 + m;
        hstride = 16 * 512;
    }

    const float2 pv = *reinterpret_cast<const float2*>(
        pair + ((size_t)n * 512 + m) * CZ + 2 * lane);
    const float4 a0 = ((const float4*)(w_b + (2 * lane) * NH))[0];
    const float4 a1 = ((const float4*)(w_b + (2 * lane) * NH))[1];
    const float4 b0 = ((const float4*)(w_b + (2 * lane + 1) * NH))[0];
    const float4 b1 = ((const float4*)(w_b + (2 * lane + 1) * NH))[1];

    float acc8[8];
    acc8[0] = pv.x * a0.x + pv.y * b0.x;
    acc8[1] = pv.x * a0.y + pv.y * b0.y;
    acc8[2] = pv.x * a0.z + pv.y * b0.z;
    acc8[3] = pv.x * a0.w + pv.y * b0.w;
    acc8[4] = pv.x * a1.x + pv.y * b1.x;
    acc8[5] = pv.x * a1.y + pv.y * b1.y;
    acc8[6] = pv.x * a1.z + pv.y * b1.z;
    acc8[7] = pv.x * a1.w + pv.y * b1.w;
#pragma unroll
    for (int h = 0; h < 8; ++h) {
#pragma unroll
        for (int off = 1; off < 64; off <<= 1)
            acc8[h] += __shfl_xor(acc8[h], off, 64);
    }
    if (lane < 8) {
        float v = acc8[0];
#pragma unroll
        for (int h = 1; h < 8; ++h) v = (lane == h) ? acc8[h] : v;
        oaddr[(size_t)lane * hstride] = v + b_b[lane];
    }
}

// ===========================================================================
// GEMM staging/compute building blocks (XOR chunk swizzle, involution both
// sides — round-5/6 verified). A-tile 128x64 bf16, B-tile(s) 64x64 bf16.
// ===========================================================================
#define STAGE_A(bufbase, k0)                                                 \
    _Pragma("unroll")                                                        \
    for (int j = 0; j < 4; ++j) {                                            \
        int Lrel = (j * 4 + w) * 1024;                                       \
        int L = Lrel + l * 16;                                               \
        int row = L >> 7;                                                    \
        int c = ((L >> 4) & 7) ^ (row & 7);                                  \
        const unsigned short* gp = A + (size_t)(bm0 + row) * 256 + (k0) + c * 8; \
        __builtin_amdgcn_global_load_lds(                                    \
            (const __attribute__((address_space(1))) void*)gp,               \
            (__attribute__((address_space(3))) void*)((char*)lds + (bufbase) + Lrel), 16, 0, 0); \
    }

#define STAGE_B(bufbase, Bofs, WTP, k0)                                      \
    _Pragma("unroll")                                                        \
    for (int j = 0; j < 2; ++j) {                                            \
        int Lrel = (j * 4 + w) * 1024;                                       \
        int L = Lrel + l * 16;                                               \
        int row = L >> 7;                                                    \
        int c = ((L >> 4) & 7) ^ (row & 7);                                  \
        const unsigned short* gp = (WTP) + (size_t)(bn0 + row) * 256 + (k0) + c * 8; \
        __builtin_amdgcn_global_load_lds(                                    \
            (const __attribute__((address_space(1))) void*)gp,               \
            (__attribute__((address_space(3))) void*)((char*)lds + (bufbase) + (Bofs) + Lrel), 16, 0, 0); \
    }

#define LOAD_AFRAG(afr, bufbase, kh)                                         \
    _Pragma("unroll")                                                        \
    for (int m = 0; m < 4; ++m) {                                            \
        int row = wm * 64 + m * 16 + (l & 15);                               \
        int c = ((kh) * 4 + (l >> 4)) ^ (row & 7);                           \
        afr[m] = *reinterpret_cast<const bf16x8*>(                           \
            (const char*)lds + (bufbase) + row * 128 + c * 16);              \
    }

#define LOAD_BFRAG(bfr, bufbase, Bofs, kh)                                   \
    _Pragma("unroll")                                                        \
    for (int nf = 0; nf < 2; ++nf) {                                         \
        int nr = wn * 32 + nf * 16 + (l & 15);                               \
        int c = ((kh) * 4 + (l >> 4)) ^ (nr & 7);                            \
        bfr[nf] = *reinterpret_cast<const bf16x8*>(                          \
            (const char*)lds + (bufbase) + (Bofs) + nr * 128 + c * 16);      \
    }

// ---------------------------------------------------------------------------
// Fused Q/K/V GEMM: stages the A-tile ONCE, three B-tiles; 48 MFMA per wave
// per K-step. 2-phase double-buffer: STAGE(next) issued before COMPUTE(cur),
// single __syncthreads (vmcnt drain) per K-step. Buffer = 40960 B.
// ---------------------------------------------------------------------------
__global__ __launch_bounds__(256) void qkv_gemm_kernel(
    const unsigned short* __restrict__ A,
    const unsigned short* __restrict__ WT0,
    const unsigned short* __restrict__ WT1,
    const unsigned short* __restrict__ WT2,
    const float* __restrict__ bq,
    const float* __restrict__ bk,
    const float* __restrict__ bv,
    unsigned short* __restrict__ Oq,
    unsigned short* __restrict__ Ok,
    unsigned short* __restrict__ Ov)
{
    __shared__ __align__(16) unsigned short lds[40960];  // 2 x (16KB A + 24KB B)

    const int t = threadIdx.x;
    const int l = t & 63;
    const int w = t >> 6;
    const int wm = w >> 1, wn = w & 1;
    const int bn0 = blockIdx.x * 64;
    const int bm0 = blockIdx.y * 128;

    const unsigned short* WT[3] = {WT0, WT1, WT2};
    f32x4 acc[3][4][2] = {};

#define QKV_STAGE(bufbase, k0)                                               \
    {                                                                        \
        STAGE_A(bufbase, k0)                                                 \
        _Pragma("unroll")                                                    \
        for (int widx = 0; widx < 3; ++widx) {                               \
            STAGE_B(bufbase, 16384 + widx * 8192, WT[widx], k0)              \
        }                                                                    \
    }

#define QKV_COMPUTE(bufbase)                                                 \
    _Pragma("unroll")                                                        \
    for (int kh = 0; kh < 2; ++kh) {                                         \
        bf16x8 a[4];                                                         \
        LOAD_AFRAG(a, bufbase, kh)                                           \
        _Pragma("unroll")                                                    \
        for (int widx = 0; widx < 3; ++widx) {                               \
            bf16x8 b[2];                                                     \
            LOAD_BFRAG(b, bufbase, 16384 + widx * 8192, kh)                  \
            _Pragma("unroll")                                                \
            for (int m = 0; m < 4; ++m)                                      \
                _Pragma("unroll")                                            \
                for (int nf = 0; nf < 2; ++nf)                               \
                    acc[widx][m][nf] = __builtin_amdgcn_mfma_f32_16x16x32_bf16( \
                        a[m], b[nf], acc[widx][m][nf], 0, 0, 0);             \
        }                                                                    \
    }

    QKV_STAGE(0, 0)
    __syncthreads();
    QKV_STAGE(40960, 64)
    QKV_COMPUTE(0)
    __syncthreads();
    QKV_STAGE(0, 128)
    QKV_COMPUTE(40960)
    __syncthreads();
    QKV_STAGE(40960, 192)
    QKV_COMPUTE(0)
    __syncthreads();
    QKV_COMPUTE(40960)

    const float* bptr[3] = {bq, bk, bv};
    unsigned short* optr[3] = {Oq, Ok, Ov};
#pragma unroll
    for (int widx = 0; widx < 3; ++widx) {
#pragma unroll
        for (int m = 0; m < 4; ++m) {
#pragma unroll
            for (int nf = 0; nf < 2; ++nf) {
                int col = bn0 + wn * 32 + nf * 16 + (l & 15);
                float bv_ = bptr[widx][col];
#pragma unroll
                for (int r = 0; r < 4; ++r) {
                    int row = bm0 + wm * 64 + m * 16 + (l >> 4) * 4 + r;
                    optr[widx][(size_t)row * 256 + col] = f2bf(acc[widx][m][nf][r] + bv_);
                }
            }
        }
    }
#undef QKV_STAGE
#undef QKV_COMPUTE
}

// ---------------------------------------------------------------------------
// Out-projection GEMM + residual, fp32 out. Same 2-phase dbuf (24576 B bufs).
// ---------------------------------------------------------------------------
__global__ __launch_bounds__(256) void out_gemm_kernel(
    const unsigned short* __restrict__ A,
    const unsigned short* __restrict__ WTp,
    const float* __restrict__ bias,
    const float* __restrict__ resid,
    float* __restrict__ C)
{
    __shared__ __align__(16) unsigned short lds[24576];  // 2 x (16KB A + 8KB B)

    const int t = threadIdx.x;
    const int l = t & 63;
    const int w = t >> 6;
    const int wm = w >> 1, wn = w & 1;
    const int bn0 = blockIdx.x * 64;
    const int bm0 = blockIdx.y * 128;

    f32x4 acc[4][2] = {};

#define OUT_STAGE(bufbase, k0)                                               \
    {                                                                        \
        STAGE_A(bufbase, k0)                                                 \
        STAGE_B(bufbase, 16384, WTp, k0)                                     \
    }

#define OUT_COMPUTE(bufbase)                                                 \
    _Pragma("unroll")                                                        \
    for (int kh = 0; kh < 2; ++kh) {                                         \
        bf16x8 a[4], b[2];                                                   \
        LOAD_AFRAG(a, bufbase, kh)                                           \
        LOAD_BFRAG(b, bufbase, 16384, kh)                                    \
        _Pragma("unroll")                                                    \
        for (int m = 0; m < 4; ++m)                                          \
            _Pragma("unroll")                                                \
            for (int nf = 0; nf < 2; ++nf)                                   \
                acc[m][nf] = __builtin_amdgcn_mfma_f32_16x16x32_bf16(        \
                    a[m], b[nf], acc[m][nf], 0, 0, 0);                       \
    }

    OUT_STAGE(0, 0)
    __syncthreads();
    OUT_STAGE(24576, 64)
    OUT_COMPUTE(0)
    __syncthreads();
    OUT_STAGE(0, 128)
    OUT_COMPUTE(24576)
    __syncthreads();
    OUT_STAGE(24576, 192)
    OUT_COMPUTE(0)
    __syncthreads();
    OUT_COMPUTE(24576)

#pragma unroll
    for (int m = 0; m < 4; ++m) {
#pragma unroll
        for (int nf = 0; nf < 2; ++nf) {
            int col = bn0 + wn * 32 + nf * 16 + (l & 15);
            float bv = bias[col];
#pragma unroll
            for (int r = 0; r < 4; ++r) {
                int row = bm0 + wm * 64 + m * 16 + (l >> 4) * 4 + r;
                C[(size_t)row * 256 + col] =
                    acc[m][nf][r] + bv + resid[(size_t)row * 256 + col];
            }
        }
    }
#undef OUT_STAGE
#undef OUT_COMPUTE
}

// ---------------------------------------------------------------------------
// Sparse attention v2 (round-6 verified). Block = (s,h), 512 threads.
// ---------------------------------------------------------------------------
__global__ __launch_bounds__(512) void attn2_kernel(
    const unsigned short* __restrict__ qb,
    const unsigned short* __restrict__ kb,
    const unsigned short* __restrict__ vb,
    const float* __restrict__ biasD,
    const float* __restrict__ biasG,
    const float* __restrict__ biasR,
    unsigned short* __restrict__ outp)
{
    __shared__ unsigned short kT[32][512];
    __shared__ unsigned short vT[32][512];

    const int t = threadIdx.x;
    const int h = blockIdx.x >> 5;
    const int s = blockIdx.x & 31;
    const float scale = 0.17677669529663687f;

    {
        const unsigned short* kr = kb + ((size_t)((s << 9) + t)) * 256 + h * 32;
        const unsigned short* vr = vb + ((size_t)((s << 9) + t)) * 256 + h * 32;
        union { uint4 q4[4]; unsigned short u[32]; } kk, vv;
#pragma unroll
        for (int i = 0; i < 4; ++i) {
            kk.q4[i] = ((const uint4*)kr)[i];
            vv.q4[i] = ((const uint4*)vr)[i];
        }
#pragma unroll
        for (int d = 0; d < 32; ++d) {
            kT[d][t] = kk.u[d];
            vT[d][t] = vv.u[d];
        }
    }
    __syncthreads();

    if (blockIdx.y == 0) {
        const int q = t;
        if (q < 16) return;

        float qr[32];
        {
            const unsigned short* qrow = qb + ((size_t)((s << 9) + q)) * 256 + h * 32;
            union { uint4 q4[4]; unsigned short u[32]; } qq;
#pragma unroll
            for (int i = 0; i < 4; ++i) qq.q4[i] = ((const uint4*)qrow)[i];
#pragma unroll
            for (int d = 0; d < 32; ++d) qr[d] = bf1(qq.u[d]) * scale;
        }

        float m_run = -1e30f, l_run = 0.f;
        float acc[32];
#pragma unroll
        for (int d = 0; d < 32; ++d) acc[d] = 0.f;

        const float* bG = biasG + (size_t)(h * 16) * 512 + q;
        for (int i = 0; i < 8; ++i) {
            const int m0 = 2 * i;
            float s0 = 0.f, s1 = 0.f;
#pragma unroll
            for (int d = 0; d < 32; ++d) {
                unsigned u = *(const unsigned*)&kT[d][m0];
                s0 = fmaf(qr[d], bflo(u), s0);
                s1 = fmaf(qr[d], bfhi(u), s1);
            }
            float x0 = s0 + bG[(size_t)m0 * 512];
            float x1 = s1 + bG[(size_t)(m0 + 1) * 512];
            float mx = fmaxf(x0, x1);
            if (mx > m_run) {
                float corr = __expf(m_run - mx);
                m_run = mx; l_run *= corr;
#pragma unroll
                for (int d = 0; d < 32; ++d) acc[d] *= corr;
            }
            float e0 = __expf(x0 - m_run);
            float e1 = __expf(x1 - m_run);
            l_run += e0 + e1;
#pragma unroll
            for (int d = 0; d < 32; ++d) {
                unsigned u = *(const unsigned*)&vT[d][m0];
                acc[d] = fmaf(e0, bflo(u), acc[d]);
                acc[d] = fmaf(e1, bfhi(u), acc[d]);
            }
        }

        const int lo = (q - 16 < 16) ? 16 : q - 16;
        const int hi = (q + 16 > 511) ? 511 : q + 16;
        const int start = (q - 16) & ~1;
        const float* bD = biasD + (size_t)(h * 33) * 512 + q;
        for (int i = 0; i < 18; ++i) {
            const int m0 = start + 2 * i;
            const int mc = (m0 > 510) ? 510 : m0;
            const bool v0 = (m0 >= lo) & (m0 <= hi);
            const bool v1 = (m0 + 1 >= lo) & (m0 + 1 <= hi);
            float s0 = 0.f, s1 = 0.f;
#pragma unroll
            for (int d = 0; d < 32; ++d) {
                unsigned u = *(const unsigned*)&kT[d][mc];
                s0 = fmaf(qr[d], bflo(u), s0);
                s1 = fmaf(qr[d], bfhi(u), s1);
            }
            int o0 = m0 - q + 16;     o0 = o0 < 0 ? 0 : (o0 > 32 ? 32 : o0);
            int o1 = m0 + 1 - q + 16; o1 = o1 < 0 ? 0 : (o1 > 32 ? 32 : o1);
            float x0 = v0 ? (s0 + bD[(size_t)o0 * 512]) : -1e30f;
            float x1 = v1 ? (s1 + bD[(size_t)o1 * 512]) : -1e30f;
            float mx = fmaxf(x0, x1);
            if (mx > m_run) {
                float corr = __expf(m_run - mx);
                m_run = mx; l_run *= corr;
#pragma unroll
                for (int d = 0; d < 32; ++d) acc[d] *= corr;
            }
            float e0 = v0 ? __expf(x0 - m_run) : 0.f;
            float e1 = v1 ? __expf(x1 - m_run) : 0.f;
            l_run += e0 + e1;
#pragma unroll
            for (int d = 0; d < 32; ++d) {
                unsigned u = *(const unsigned*)&vT[d][mc];
                acc[d] = fmaf(e0, bflo(u), acc[d]);
                acc[d] = fmaf(e1, bfhi(u), acc[d]);
            }
        }

        const float inv = 1.0f / l_run;
        union { uint4 q4[4]; unsigned short u[32]; } oo;
#pragma unroll
        for (int d = 0; d < 32; ++d) oo.u[d] = f2bf(acc[d] * inv);
        unsigned short* orow = outp + ((size_t)((s << 9) + q)) * 256 + h * 32;
#pragma unroll
        for (int i = 0; i < 4; ++i) ((uint4*)orow)[i] = oo.q4[i];
    } else {
        const int wv = t >> 6, lane = t & 63;
        for (int qi = 0; qi < 2; ++qi) {
            const int q = wv * 2 + qi;
            float qr[32];
            {
                const unsigned short* qrow = qb + ((size_t)((s << 9) + q)) * 256 + h * 32;
                union { uint4 q4[4]; unsigned short u[32]; } qq;
#pragma unroll
                for (int i = 0; i < 4; ++i) qq.q4[i] = ((const uint4*)qrow)[i];
#pragma unroll
                for (int d = 0; d < 32; ++d) qr[d] = bf1(qq.u[d]) * scale;
            }
            float m_loc = -1e30f, l_loc = 0.f;
            float accl[32];
#pragma unroll
            for (int d = 0; d < 32; ++d) accl[d] = 0.f;

            const float* bR = biasR + (size_t)(h * 16 + q) * 512;
            for (int j = 0; j < 8; ++j) {
                const int m = j * 64 + lane;
                float sc = 0.f;
#pragma unroll
                for (int d = 0; d < 32; ++d)
                    sc = fmaf(qr[d], bf1(kT[d][m]), sc);
                float x = sc + bR[m];
                if (x > m_loc) {
                    float corr = __expf(m_loc - x);
                    m_loc = x; l_loc *= corr;
#pragma unroll
                    for (int d = 0; d < 32; ++d) accl[d] *= corr;
                }
                float e = __expf(x - m_loc);
                l_loc += e;
#pragma unroll
                for (int d = 0; d < 32; ++d)
                    accl[d] = fmaf(e, bf1(vT[d][m]), accl[d]);
            }
            float mg = m_loc;
#pragma unroll
            for (int off = 1; off < 64; off <<= 1)
                mg = fmaxf(mg, __shfl_xor(mg, off, 64));
            float cf = __expf(m_loc - mg);
            float lg = l_loc * cf;
#pragma unroll
            for (int off = 1; off < 64; off <<= 1)
                lg += __shfl_xor(lg, off, 64);
            const float inv = 1.0f / lg;
            union { uint4 q4[4]; unsigned short u[32]; } oo;
#pragma unroll
            for (int d = 0; d < 32; ++d) {
                float a = accl[d] * cf;
#pragma unroll
                for (int off = 1; off < 64; off <<= 1)
                    a += __shfl_xor(a, off, 64);
                oo.u[d] = f2bf(a * inv);
            }
            if (lane == 0) {
                unsigned short* orow = outp + ((size_t)((s << 9) + q)) * 256 + h * 32;
#pragma unroll
                for (int i = 0; i < 4; ++i) ((uint4*)orow)[i] = oo.q4[i];
            }
        }
    }
}

// ---------------------------------------------------------------------------
// LayerNorm over CM=256, in place. One wave per row.
// ---------------------------------------------------------------------------
__global__ __launch_bounds__(256) void ln_kernel(
    const float* __restrict__ y,
    const float* __restrict__ g,
    const float* __restrict__ b,
    float* __restrict__ outp)
{
    int t = threadIdx.x;
    int wave = t >> 6, lane = t & 63;
    int row = blockIdx.x * 4 + wave;

    const float4 yv = *reinterpret_cast<const float4*>(y + (size_t)row * CM + lane * 4);
    float s  = yv.x + yv.y + yv.z + yv.w;
    float sq = yv.x * yv.x + yv.y * yv.y + yv.z * yv.z + yv.w * yv.w;
#pragma unroll
    for (int off = 1; off < 64; off <<= 1) {
        s  += __shfl_xor(s, off, 64);
        sq += __shfl_xor(sq, off, 64);
    }
    float mu  = s * (1.0f / CM);
    float var = sq * (1.0f / CM) - mu * mu;
    float r   = rsqrtf(var + 1e-5f);

    float4 gv = *reinterpret_cast<const float4*>(g + lane * 4);
    float4 bv = *reinterpret_cast<const float4*>(b + lane * 4);
    float4 o;
    o.x = (yv.x - mu) * r * gv.x + bv.x;
    o.y = (yv.y - mu) * r * gv.y + bv.y;
    o.z = (yv.z - mu) * r * gv.z + bv.z;
    o.w = (yv.w - mu) * r * gv.w + bv.w;
    *reinterpret_cast<float4*>(outp + (size_t)row * CM + lane * 4) = o;
}

// ---------------------------------------------------------------------------
extern "C" void kernel_launch(void* const* d_in, const int* in_sizes, int n_in,
                              void* d_out, int out_size, void* d_ws, size_t ws_size,
                              hipStream_t stream)
{
    const float* msa  = (const float*)d_in[0];
    const float* pair = (const float*)d_in[1];
    const float* w_q  = (const float*)d_in[2];
    const float* b_q  = (const float*)d_in[3];
    const float* w_k  = (const float*)d_in[4];
    const float* b_k  = (const float*)d_in[5];
    const float* w_v  = (const float*)d_in[6];
    const float* b_v  = (const float*)d_in[7];
    const float* w_o  = (const float*)d_in[8];
    const float* b_o  = (const float*)d_in[9];
    const float* w_b  = (const float*)d_in[10];
    const float* b_b  = (const float*)d_in[11];
    const float* ln_g = (const float*)d_in[12];
    const float* ln_b = (const float*)d_in[13];
    float* out = (float*)d_out;

    // workspace layout (~41 MB)
    float* ws    = (float*)d_ws;
    float* biasD = ws;                           // 8*33*512
    float* biasG = biasD + 8 * 33 * 512;         // 8*16*512
    float* biasR = biasG + 8 * 16 * 512;         // 8*16*512
    unsigned short* q_bf   = (unsigned short*)(biasR + 8 * 16 * 512);
    unsigned short* k_bf   = q_bf + (size_t)MROWS * CM;
    unsigned short* v_bf   = k_bf + (size_t)MROWS * CM;
    unsigned short* msa_bf = v_bf + (size_t)MROWS * CM;
    unsigned short* ao_bf  = msa_bf + (size_t)MROWS * CM;
    unsigned short* wqT = ao_bf + (size_t)MROWS * CM;
    unsigned short* wkT = wqT + CM * CM;
    unsigned short* wvT = wkT + CM * CM;
    unsigned short* woT = wvT + CM * CM;

    // 1. conversions
    cvt_msa_kernel<<<(MROWS * CM) / (256 * 8), 256, 0, stream>>>(msa, msa_bf);
    cvt_wT_kernel<<<dim3(CM * CM / 256, 4), 256, 0, stream>>>(
        w_q, w_k, w_v, w_o, wqT, wkT, wvT, woT);

    // 2. sparse pair bias
    bias_kernel<<<(NJOBS + 3) / 4, 256, 0, stream>>>(
        pair, w_b, b_b, biasD, biasG, biasR);

    // 3. fused Q/K/V projection (bf16 MFMA, 2-phase dbuf)
    dim3 gg(CM / 64, MROWS / 128);
    qkv_gemm_kernel<<<gg, 256, 0, stream>>>(
        msa_bf, wqT, wkT, wvT, b_q, b_k, b_v, q_bf, k_bf, v_bf);

    // 4. sparse attention v2 -> bf16
    attn2_kernel<<<dim3(256, 2), 512, 0, stream>>>(
        q_bf, k_bf, v_bf, biasD, biasG, biasR, ao_bf);

    // 5. output projection + residual -> d_out (fp32 y)
    out_gemm_kernel<<<gg, 256, 0, stream>>>(ao_bf, woT, b_o, msa, out);

    // 6. LayerNorm in place
    ln_kernel<<<MROWS / 4, 256, 0, stream>>>(out, ln_g, ln_b, out);
}